// Round 1
// baseline (71.841 us; speedup 1.0000x reference)
//
#include <hip/hip_runtime.h>

// LinearImputer: linear interpolation over zero runs along time axis.
// x: [B, T, D] f32, row-major. Column (b,d) scanned along t (stride D).
// Semantics (match JAX ref exactly):
//   valid = x != 0
//   prev  = last valid index <= t (-1 if none); nxt = first valid >= t (T if none)
//   interior = !valid && prev >= 0 && nxt < T
//   run_len = nxt - prev - 1; pos = t - prev - 1; denom = max(run_len-1, 1)
//   out = interior ? x[prev] + (x[nxt]-x[prev]) * (pos/denom) : x
// Boundary-touching runs stay zero.

constexpr int B = 32, T = 4096, D = 256;
constexpr int L  = 8;        // time steps per thread
constexpr int NC = T / L;    // 512 chunks per column
constexpr int C4 = D / 4;    // 64 float4-column-groups per batch row

__global__ __launch_bounds__(256)
void LinearImputer_kernel(const float* __restrict__ x, float* __restrict__ out) {
    const int g  = blockIdx.x * 256 + threadIdx.x;
    const int l  = g & (C4 - 1);        // float4 column group: d = 4*l
    const int bc = g >> 6;              // b*NC + c
    const int c  = bc & (NC - 1);
    const int b  = bc >> 9;             // NC = 512
    const int t0 = c * L;
    const int t1 = t0 + L;

    const float4* __restrict__ x4 = (const float4*)x;
    float4* __restrict__       o4 = (float4*)out;
    const size_t rowBase = (size_t)b * T;   // in time rows
    // float4 element index for time t: (rowBase + t) * (D/4) + l

    // ---- load chunk (8 x dwordx4, each wave instr = contiguous 1 KiB) ----
    float v[L][4];
    #pragma unroll
    for (int j = 0; j < L; ++j) {
        float4 tv = x4[(rowBase + (size_t)(t0 + j)) * C4 + l];
        v[j][0] = tv.x; v[j][1] = tv.y; v[j][2] = tv.z; v[j][3] = tv.w;
    }

    // ---- lazy backward halo walk: last valid strictly before t0 ----
    int   pi[4]; float pv[4];
    #pragma unroll
    for (int cc = 0; cc < 4; ++cc) { pi[cc] = -1; pv[cc] = 0.0f; }
    {
        int pending = 0;
        #pragma unroll
        for (int cc = 0; cc < 4; ++cc) if (v[0][cc] == 0.0f) pending |= (1 << cc);
        int tt = t0 - 1;
        while (pending && tt >= 0) {
            float4 h = x4[(rowBase + (size_t)tt) * C4 + l];
            float hv[4]; hv[0] = h.x; hv[1] = h.y; hv[2] = h.z; hv[3] = h.w;
            #pragma unroll
            for (int cc = 0; cc < 4; ++cc)
                if (((pending >> cc) & 1) && hv[cc] != 0.0f) {
                    pi[cc] = tt; pv[cc] = hv[cc]; pending &= ~(1 << cc);
                }
            --tt;
        }
    }

    // ---- forward sweep: per-element (prev_idx, prev_val) ----
    int piA[L][4]; float pvA[L][4];
    #pragma unroll
    for (int j = 0; j < L; ++j) {
        #pragma unroll
        for (int cc = 0; cc < 4; ++cc) {
            piA[j][cc] = pi[cc]; pvA[j][cc] = pv[cc];
            if (v[j][cc] != 0.0f) { pi[cc] = t0 + j; pv[cc] = v[j][cc]; }
        }
    }

    // ---- lazy forward halo walk: first valid at/after t1 ----
    int ni[4]; float nv[4];
    #pragma unroll
    for (int cc = 0; cc < 4; ++cc) { ni[cc] = T; nv[cc] = 0.0f; }
    {
        int pending = 0;
        #pragma unroll
        for (int cc = 0; cc < 4; ++cc) if (v[L - 1][cc] == 0.0f) pending |= (1 << cc);
        int tt = t1;
        while (pending && tt < T) {
            float4 h = x4[(rowBase + (size_t)tt) * C4 + l];
            float hv[4]; hv[0] = h.x; hv[1] = h.y; hv[2] = h.z; hv[3] = h.w;
            #pragma unroll
            for (int cc = 0; cc < 4; ++cc)
                if (((pending >> cc) & 1) && hv[cc] != 0.0f) {
                    ni[cc] = tt; nv[cc] = hv[cc]; pending &= ~(1 << cc);
                }
            ++tt;
        }
    }

    // ---- backward sweep: carry (next_idx, next_val), emit output ----
    #pragma unroll
    for (int j = L - 1; j >= 0; --j) {
        float o[4];
        #pragma unroll
        for (int cc = 0; cc < 4; ++cc) {
            float val = v[j][cc];
            if (val != 0.0f) {
                o[cc] = val; ni[cc] = t0 + j; nv[cc] = val;
            } else {
                int p = piA[j][cc];
                int n = ni[cc];
                if (p >= 0 && n < T) {
                    int start = p + 1;
                    int denom = n - start - 1;       // run_len - 1
                    if (denom < 1) denom = 1;
                    float frac = (float)(t0 + j - start) / (float)denom;
                    float xp = pvA[j][cc];
                    o[cc] = xp + (nv[cc] - xp) * frac;
                } else {
                    o[cc] = 0.0f;                    // boundary-touching run
                }
            }
        }
        float4 ov; ov.x = o[0]; ov.y = o[1]; ov.z = o[2]; ov.w = o[3];
        o4[(rowBase + (size_t)(t0 + j)) * C4 + l] = ov;
    }
}

extern "C" void kernel_launch(void* const* d_in, const int* in_sizes, int n_in,
                              void* d_out, int out_size, void* d_ws, size_t ws_size,
                              hipStream_t stream) {
    const float* x = (const float*)d_in[0];
    float* out = (float*)d_out;
    const int total_threads = B * NC * C4;   // 1,048,576
    dim3 grid(total_threads / 256), block(256);
    LinearImputer_kernel<<<grid, block, 0, stream>>>(x, out);
}

// Round 3
// 54.512 us; speedup vs baseline: 1.3179x; 1.3179x over previous
//
#include <hip/hip_runtime.h>

// LinearImputer: linear interp over zero runs along time axis (B=32,T=4096,D=256 f32).
// Semantics (match JAX ref):
//   prev = last valid <= t (-1 if none); nxt = first valid >= t (T if none)
//   interior = !valid && prev>=0 && nxt<T
//   denom = max(nxt-prev-2, 1); pos = t-prev-1; out = x[prev] + (x[nxt]-x[prev])*pos/denom
// Boundary-touching runs stay zero.
//
// Design: per-thread chunk of L=8 rows x 4 cols (f32x4 lane). Fixed W=4 halo rows
// each side prefetched UNCONDITIONALLY (issued with main loads -> no dependent-load
// serialization; deep-run fallback prob 0.3^5 per column). No per-element prev arrays:
// forward emit with prev-carry + unrolled in-chunk next-scan. NT stores for output.

typedef float f32x4 __attribute__((ext_vector_type(4)));

constexpr int B = 32, T = 4096, D = 256;
constexpr int L = 8;        // rows per thread
constexpr int W = 4;        // halo rows prefetched per side
constexpr int NC = T / L;   // 512
constexpr int C4 = D / 4;   // 64

__global__ __launch_bounds__(256)
void LinearImputer_kernel(const float* __restrict__ x, float* __restrict__ out) {
    const int g  = blockIdx.x * 256 + threadIdx.x;
    const int l  = g & (C4 - 1);        // float4 column group
    const int bc = g >> 6;
    const int c  = bc & (NC - 1);       // chunk index (wave-uniform)
    const int b  = bc >> 9;
    const int t0 = c * L;
    const int t1 = t0 + L;

    const f32x4* __restrict__ x4 = (const f32x4*)x;
    f32x4* __restrict__       o4 = (f32x4*)out;
    const size_t base = ((size_t)b * T) * C4 + l;   // f32x4 idx of (b, t=0, group l)

    const bool hasB = (c > 0);          // wave-uniform branches
    const bool hasF = (c < NC - 1);

    // ---- issue ALL loads up-front: 8 main + 4 back-halo + 4 fwd-halo ----
    f32x4 hb4[W], hf4[W];
    if (hasB) {
        #pragma unroll
        for (int w = 0; w < W; ++w) hb4[w] = x4[base + (size_t)(t0 - 1 - w) * C4];
    }
    if (hasF) {
        #pragma unroll
        for (int w = 0; w < W; ++w) hf4[w] = x4[base + (size_t)(t1 + w) * C4];
    }
    float v[L][4];
    #pragma unroll
    for (int j = 0; j < L; ++j) {
        f32x4 tv = x4[base + (size_t)(t0 + j) * C4];
        v[j][0] = tv.x; v[j][1] = tv.y; v[j][2] = tv.z; v[j][3] = tv.w;
    }

    // ---- reduce backward halo -> prev carry (pi,pv) ----
    int pi[4]; float pv[4];
    #pragma unroll
    for (int cc = 0; cc < 4; ++cc) { pi[cc] = -1; pv[cc] = 0.0f; }
    if (hasB) {
        #pragma unroll
        for (int w = 0; w < W; ++w) {
            float h[4] = {hb4[w].x, hb4[w].y, hb4[w].z, hb4[w].w};
            #pragma unroll
            for (int cc = 0; cc < 4; ++cc)
                if (pi[cc] < 0 && h[cc] != 0.0f) { pi[cc] = t0 - 1 - w; pv[cc] = h[cc]; }
        }
        // rare deep-run fallback (per-column prob 0.3^5 ~ 0.24%)
        int pending = 0;
        #pragma unroll
        for (int cc = 0; cc < 4; ++cc)
            if (v[0][cc] == 0.0f && pi[cc] < 0) pending |= (1 << cc);
        int tt = t0 - 1 - W;
        while (pending && tt >= 0) {
            f32x4 hq = x4[base + (size_t)tt * C4];
            float h[4] = {hq.x, hq.y, hq.z, hq.w};
            #pragma unroll
            for (int cc = 0; cc < 4; ++cc)
                if (((pending >> cc) & 1) && h[cc] != 0.0f) {
                    pi[cc] = tt; pv[cc] = h[cc]; pending &= ~(1 << cc);
                }
            --tt;
        }
    }

    // ---- reduce forward halo -> next (ni,nv) ----
    int ni[4]; float nv[4];
    #pragma unroll
    for (int cc = 0; cc < 4; ++cc) { ni[cc] = T; nv[cc] = 0.0f; }
    if (hasF) {
        #pragma unroll
        for (int w = 0; w < W; ++w) {
            float h[4] = {hf4[w].x, hf4[w].y, hf4[w].z, hf4[w].w};
            #pragma unroll
            for (int cc = 0; cc < 4; ++cc)
                if (ni[cc] == T && h[cc] != 0.0f) { ni[cc] = t1 + w; nv[cc] = h[cc]; }
        }
        int pending = 0;
        #pragma unroll
        for (int cc = 0; cc < 4; ++cc)
            if (v[L - 1][cc] == 0.0f && ni[cc] == T) pending |= (1 << cc);
        int tt = t1 + W;
        while (pending && tt < T) {
            f32x4 hq = x4[base + (size_t)tt * C4];
            float h[4] = {hq.x, hq.y, hq.z, hq.w};
            #pragma unroll
            for (int cc = 0; cc < 4; ++cc)
                if (((pending >> cc) & 1) && h[cc] != 0.0f) {
                    ni[cc] = tt; nv[cc] = h[cc]; pending &= ~(1 << cc);
                }
            ++tt;
        }
    }

    // ---- forward emit: prev-carry + unrolled in-chunk next-scan ----
    #pragma unroll
    for (int j = 0; j < L; ++j) {
        float o[4];
        #pragma unroll
        for (int cc = 0; cc < 4; ++cc) {
            float val = v[j][cc];
            if (val != 0.0f) {
                o[cc] = val; pi[cc] = t0 + j; pv[cc] = val;
            } else {
                // nearest in-chunk next wins (reverse unroll), else halo next
                int nxi = ni[cc]; float nxv = nv[cc];
                #pragma unroll
                for (int k = L - 1; k > j; --k)
                    if (v[k][cc] != 0.0f) { nxi = t0 + k; nxv = v[k][cc]; }
                if (pi[cc] >= 0 && nxi < T) {
                    int denom = nxi - pi[cc] - 2;        // run_len - 1
                    if (denom < 1) denom = 1;
                    float frac = __fdividef((float)(t0 + j - pi[cc] - 1), (float)denom);
                    o[cc] = pv[cc] + (nxv - pv[cc]) * frac;
                } else {
                    o[cc] = 0.0f;                        // boundary-touching run
                }
            }
        }
        f32x4 ov; ov.x = o[0]; ov.y = o[1]; ov.z = o[2]; ov.w = o[3];
        __builtin_nontemporal_store(ov, &o4[base + (size_t)(t0 + j) * C4]);
    }
}

extern "C" void kernel_launch(void* const* d_in, const int* in_sizes, int n_in,
                              void* d_out, int out_size, void* d_ws, size_t ws_size,
                              hipStream_t stream) {
    const float* x = (const float*)d_in[0];
    float* out = (float*)d_out;
    const int total_threads = B * NC * C4;   // 1,048,576
    dim3 grid(total_threads / 256), block(256);
    LinearImputer_kernel<<<grid, block, 0, stream>>>(x, out);
}